// Round 2
// baseline (396.334 us; speedup 1.0000x reference)
//
#include <hip/hip_runtime.h>
#include <stdint.h>

// out[b][o] = clamp((sum_k x[b][k]*W[o][k] + t[o]) >> (-n[o]), act_min[o], act_max[o])
// B=8192, IN=4096, OUT=4096. x,W arrive int32; harness reads d_out as int32.
//
// R12: 2 waves/SIMD. R10 (flat, register-stream) and R11 (LDS-shared) both pinned
// at MfmaUtil=45% with identical duration despite 2x different L2 traffic -> the
// cap is single-wave-per-SIMD MFMA issue, not bandwidth. Every >50% reference
// (8-phase 256^2=62%, HK=70-76%) runs 2 waves/SIMD. Now: 8 waves (512 thr),
// block tile 256x256, wave tile 128x64 (acc=128 regs, ~200 VGPR total, forced
// by __launch_bounds__(512,2)). Same 4-buffer counted-vmcnt schedule: per phase
// 2 global_load_lds + 6 ds_read_b128 + 8 MFMA per wave, vmcnt(2) (never 0).

#define BDIM 8192
#define INDIM 4096
#define OUTDIM 4096

typedef __attribute__((ext_vector_type(4))) int I4;
typedef __attribute__((ext_vector_type(16))) int I16;

// ---------------- pack: int32 -> int8 fragment order, LDS transpose ----------
// Fragment layout: byte off = ((m32*128 + kb)*64 + lane)*16 + b,
// where row = m32*32 + (lane&31), k = kb*32 + (lane>>5)*16 + b.
__global__ __launch_bounds__(256) void pack_lds(const int* __restrict__ x,
                                                const int* __restrict__ W,
                                                uint32_t* __restrict__ xp,
                                                uint32_t* __restrict__ wp) {
    __shared__ uint32_t sb[8192];  // 32 KB
    const int tid = threadIdx.x;
    const int bid = blockIdx.x;
    const int* src;
    uint32_t* dst;
    if (bid < 1024) {
        const int m32 = bid >> 2, q = bid & 3;
        src = x + (size_t)m32 * 32 * INDIM + q * 1024;
        dst = xp + (size_t)m32 * 32768 + q * 8192;
    } else {
        const int v = bid - 1024;
        const int n32 = v >> 2, q = v & 3;
        src = W + (size_t)n32 * 32 * INDIM + q * 1024;
        dst = wp + (size_t)n32 * 32768 + q * 8192;
    }
    const int kb_l = tid >> 3;                 // local kb (k/32 within chunk)
    const int lane_hi = ((tid >> 2) & 1) << 5; // (k>>4)&1 -> lane bit 5
    const int bslot = tid & 3;                 // byte-word slot within lane's 16B
#pragma unroll 4
    for (int rr = 0; rr < 32; ++rr) {
        int4 a = *(const int4*)(src + (size_t)rr * INDIM + tid * 4);
        uint32_t v = ((uint32_t)a.x & 255u) | (((uint32_t)a.y & 255u) << 8)
                   | (((uint32_t)a.z & 255u) << 16) | (((uint32_t)a.w & 255u) << 24);
        uint32_t idx = (uint32_t)(kb_l * 256 + (rr + lane_hi) * 4 + bslot);
        idx ^= ((idx >> 8) & 7u) << 2;  // XOR-swizzle: 16-way -> 2-way (free)
        sb[idx] = v;
    }
    __syncthreads();
#pragma unroll
    for (int it = 0; it < 8; ++it) {
        uint32_t idx = (uint32_t)(it * 1024 + tid * 4);
        idx ^= ((idx >> 8) & 7u) << 2;
        uint4 vv = *(const uint4*)&sb[idx];
        *(uint4*)(dst + it * 1024 + tid * 4) = vv;
    }
}

// ---------------- GEMM: 8 waves/block, 256x256 tile, wave tile 128x64 --------
__device__ __forceinline__ void glds16(const void* g, void* l) {
    __builtin_amdgcn_global_load_lds((__attribute__((address_space(1))) void*)g,
                                     (__attribute__((address_space(3))) void*)l,
                                     16, 0, 0);
}

#define VMW4() asm volatile("s_waitcnt vmcnt(4)" ::: "memory")
#define VMW2() asm volatile("s_waitcnt vmcnt(2)" ::: "memory")
#define VMW0() asm volatile("s_waitcnt vmcnt(0)" ::: "memory")
#define BARRIER()                          \
    do {                                   \
        __builtin_amdgcn_s_barrier();      \
        asm volatile("" ::: "memory");     \
    } while (0)
#define SCHEDB() __builtin_amdgcn_sched_barrier(0)

// stage set SETK into buffer BUF: this wave's 2 subtiles (1 KB each)
#define STAGE(SETK, BUF)                                                          \
    do {                                                                          \
        _Pragma("unroll")                                                         \
        for (int i_ = 0; i_ < 2; ++i_)                                            \
            glds16(gsrc[i_] + (size_t)(SETK) * 1024,                              \
                   lds_raw + (BUF) * 16384 + (w * 2 + i_) * 1024);                \
    } while (0)

// read this wave's 6 fragments of one set from buffer BUF (compile-time)
#define FRAG_READ(FA, FB, BUF)                                                    \
    do {                                                                          \
        const uint8_t* lb_ = lds_raw + (BUF) * 16384 + lane * 16;                 \
        _Pragma("unroll")                                                         \
        for (int i_ = 0; i_ < 4; ++i_)                                            \
            FA[i_] = *(const I4*)(lb_ + (wr4 + i_) * 1024);                       \
        _Pragma("unroll")                                                         \
        for (int j_ = 0; j_ < 2; ++j_)                                            \
            FB[j_] = *(const I4*)(lb_ + 8192 + (wc2 + j_) * 1024);                \
    } while (0)

#define MFMA_SET(FA, FB)                                                          \
    do {                                                                          \
        _Pragma("unroll")                                                         \
        for (int i_ = 0; i_ < 4; ++i_)                                            \
            _Pragma("unroll")                                                     \
            for (int j_ = 0; j_ < 2; ++j_)                                        \
                acc[i_][j_] = __builtin_amdgcn_mfma_i32_32x32x32_i8(              \
                    FA[i_], FB[j_], acc[i_][j_], 0, 0, 0);                        \
    } while (0)

__global__ __launch_bounds__(512, 2) void gemm_lds(
    const uint8_t* __restrict__ Xp,   // fragment-ordered
    const uint8_t* __restrict__ Wp,   // fragment-ordered
    const int* __restrict__ t, const int* __restrict__ nsh,
    const int* __restrict__ amin, const int* __restrict__ amax,
    int* __restrict__ out) {

    const int bn = blockIdx.x;       // 0..15 (OUT tiles of 256) — fast axis
    const int bm = blockIdx.y;       // 0..31
    const int tid = threadIdx.x;
    const int lane = tid & 63;
    const int w = tid >> 6;          // wave 0..7
    const int wr = w >> 2;           // wave row (0..1): rows wr*128..+128
    const int wc = w & 3;            // wave col (0..3): cols wc*64..+64
    const int wr4 = wr * 4;
    const int wc2 = wc * 2;

    __shared__ uint8_t lds_raw[65536];  // 4 buffers x (8 A + 8 B subtiles) x 1 KB

    // wave w stages subtiles s = 2w, 2w+1 (s<8: A row-tiles; s>=8: B col-tiles)
    const uint8_t* gsrc[2];
#pragma unroll
    for (int i = 0; i < 2; ++i) {
        const int s = w * 2 + i;
        gsrc[i] = (s < 8) ? Xp + ((size_t)(bm * 8 + s) << 17) + lane * 16
                          : Wp + ((size_t)(bn * 8 + (s - 8)) << 17) + lane * 16;
    }

    I16 acc[4][2];
#pragma unroll
    for (int i = 0; i < 4; ++i)
#pragma unroll
        for (int j = 0; j < 2; ++j)
#pragma unroll
            for (int r = 0; r < 16; ++r) acc[i][j][r] = 0;

    I4 a0[4], b0[2], a1[4], b1[2];

    // prologue: stage sets 0..2 (6 vmem/wave), confirm set 0, preload its frags
    STAGE(0, 0);
    STAGE(1, 1);
    STAGE(2, 2);
    VMW4();
    BARRIER();
    FRAG_READ(a0, b0, 0);

    // main loop: 4 sets/iter. Phase P_k: vmcnt(2) confirms set k+1 (set k+2
    // still in flight), barrier, stage k+3, preload frags k+1, MFMA set k.
#pragma unroll 1
    for (int kk = 0; kk < 124; kk += 4) {
        VMW2(); BARRIER();
        STAGE(kk + 3, 3);
        FRAG_READ(a1, b1, 1);
        MFMA_SET(a0, b0);       // set kk
        SCHEDB();
        VMW2(); BARRIER();
        STAGE(kk + 4, 0);
        FRAG_READ(a0, b0, 2);
        MFMA_SET(a1, b1);       // set kk+1
        SCHEDB();
        VMW2(); BARRIER();
        STAGE(kk + 5, 1);
        FRAG_READ(a1, b1, 3);
        MFMA_SET(a0, b0);       // set kk+2
        SCHEDB();
        VMW2(); BARRIER();
        STAGE(kk + 6, 2);
        FRAG_READ(a0, b0, 0);
        MFMA_SET(a1, b1);       // set kk+3
        SCHEDB();
    }
    // peel: sets 124..127 (stages 127; vmcnt tapers 2,2,0)
    VMW2(); BARRIER();
    STAGE(127, 3);
    FRAG_READ(a1, b1, 1);       // set 125
    MFMA_SET(a0, b0);           // set 124
    SCHEDB();
    VMW2(); BARRIER();
    FRAG_READ(a0, b0, 2);       // set 126
    MFMA_SET(a1, b1);           // set 125
    SCHEDB();
    VMW0(); BARRIER();
    FRAG_READ(a1, b1, 3);       // set 127
    MFMA_SET(a0, b0);           // set 126
    SCHEDB();
    MFMA_SET(a1, b1);           // set 127

    // epilogue: 32x32 C/D layout col=lane&31, row=(reg&3)+8*(reg>>2)+4*(lane>>5)
#pragma unroll
    for (int j = 0; j < 2; ++j) {
        const int o = bn * 256 + wc2 * 32 + j * 32 + (lane & 31);
        const int tt = t[o];
        const int sh = -nsh[o];
        const int mn = amin[o];
        const int mx = amax[o];
#pragma unroll
        for (int i = 0; i < 4; ++i) {
            const int rowbase = bm * 256 + wr4 * 32 + i * 32 + 4 * (lane >> 5);
#pragma unroll
            for (int r = 0; r < 16; ++r) {
                const int row = rowbase + (r & 3) + 8 * (r >> 2);
                int v = acc[i][j][r] + tt;
                v >>= sh;
                v = v < mn ? mn : (v > mx ? mx : v);
                __builtin_nontemporal_store(v, &out[(size_t)row * OUTDIM + o]);
            }
        }
    }
}

extern "C" void kernel_launch(void* const* d_in, const int* in_sizes, int n_in,
                              void* d_out, int out_size, void* d_ws, size_t ws_size,
                              hipStream_t stream) {
    const int* x = (const int*)d_in[0];
    const int* W = (const int*)d_in[1];
    const int* t = (const int*)d_in[2];
    const int* n = (const int*)d_in[3];
    const int* amin = (const int*)d_in[4];
    const int* amax = (const int*)d_in[5];
    int* out = (int*)d_out;

    uint8_t* xp = (uint8_t*)d_ws;                    // 33554432 B (fragment order)
    uint8_t* wp = xp + (size_t)BDIM * INDIM;         // 16777216 B (fragment order)

    pack_lds<<<1536, 256, 0, stream>>>(x, W, (uint32_t*)xp, (uint32_t*)wp);

    dim3 grid(OUTDIM / 256, BDIM / 256);  // (16 bn fast, 32 bm) = 512 blocks
    gemm_lds<<<grid, 512, 0, stream>>>(xp, wp, t, n, amin, amax, out);
}

// Round 3
// 389.837 us; speedup vs baseline: 1.0167x; 1.0167x over previous
//
#include <hip/hip_runtime.h>
#include <stdint.h>

// out[b][o] = clamp((sum_k x[b][k]*W[o][k] + t[o]) >> (-n[o]), act_min[o], act_max[o])
// B=8192, IN=4096, OUT=4096. x,W arrive int32; harness reads d_out as int32.
//
// R13: R12 + T5 (s_setprio around MFMA cluster). R12 got 2 waves/SIMD
// (occupancy 10.8->20.8) but MfmaUtil only 45->50.5: lockstep waves stall at
// the same barrier. setprio(1) around the MFMA burst lets the CU scheduler
// favor the MFMA-entering wave over its sibling's stage/ds_read phase --
// proven +21-25% on exactly this counted-vmcnt phase structure (m218b/m224),
// null on structures without role diversity (m190). Everything else unchanged.

#define BDIM 8192
#define INDIM 4096
#define OUTDIM 4096

typedef __attribute__((ext_vector_type(4))) int I4;
typedef __attribute__((ext_vector_type(16))) int I16;

// ---------------- pack: int32 -> int8 fragment order, LDS transpose ----------
// Fragment layout: byte off = ((m32*128 + kb)*64 + lane)*16 + b,
// where row = m32*32 + (lane&31), k = kb*32 + (lane>>5)*16 + b.
__global__ __launch_bounds__(256) void pack_lds(const int* __restrict__ x,
                                                const int* __restrict__ W,
                                                uint32_t* __restrict__ xp,
                                                uint32_t* __restrict__ wp) {
    __shared__ uint32_t sb[8192];  // 32 KB
    const int tid = threadIdx.x;
    const int bid = blockIdx.x;
    const int* src;
    uint32_t* dst;
    if (bid < 1024) {
        const int m32 = bid >> 2, q = bid & 3;
        src = x + (size_t)m32 * 32 * INDIM + q * 1024;
        dst = xp + (size_t)m32 * 32768 + q * 8192;
    } else {
        const int v = bid - 1024;
        const int n32 = v >> 2, q = v & 3;
        src = W + (size_t)n32 * 32 * INDIM + q * 1024;
        dst = wp + (size_t)n32 * 32768 + q * 8192;
    }
    const int kb_l = tid >> 3;                 // local kb (k/32 within chunk)
    const int lane_hi = ((tid >> 2) & 1) << 5; // (k>>4)&1 -> lane bit 5
    const int bslot = tid & 3;                 // byte-word slot within lane's 16B
#pragma unroll 4
    for (int rr = 0; rr < 32; ++rr) {
        int4 a = *(const int4*)(src + (size_t)rr * INDIM + tid * 4);
        uint32_t v = ((uint32_t)a.x & 255u) | (((uint32_t)a.y & 255u) << 8)
                   | (((uint32_t)a.z & 255u) << 16) | (((uint32_t)a.w & 255u) << 24);
        uint32_t idx = (uint32_t)(kb_l * 256 + (rr + lane_hi) * 4 + bslot);
        idx ^= ((idx >> 8) & 7u) << 2;  // XOR-swizzle: 16-way -> 2-way (free)
        sb[idx] = v;
    }
    __syncthreads();
#pragma unroll
    for (int it = 0; it < 8; ++it) {
        uint32_t idx = (uint32_t)(it * 1024 + tid * 4);
        idx ^= ((idx >> 8) & 7u) << 2;
        uint4 vv = *(const uint4*)&sb[idx];
        *(uint4*)(dst + it * 1024 + tid * 4) = vv;
    }
}

// ---------------- GEMM: 8 waves/block, 256x256 tile, wave tile 128x64 --------
__device__ __forceinline__ void glds16(const void* g, void* l) {
    __builtin_amdgcn_global_load_lds((__attribute__((address_space(1))) void*)g,
                                     (__attribute__((address_space(3))) void*)l,
                                     16, 0, 0);
}

#define VMW4() asm volatile("s_waitcnt vmcnt(4)" ::: "memory")
#define VMW2() asm volatile("s_waitcnt vmcnt(2)" ::: "memory")
#define VMW0() asm volatile("s_waitcnt vmcnt(0)" ::: "memory")
#define BARRIER()                          \
    do {                                   \
        __builtin_amdgcn_s_barrier();      \
        asm volatile("" ::: "memory");     \
    } while (0)
#define SCHEDB() __builtin_amdgcn_sched_barrier(0)

// stage set SETK into buffer BUF: this wave's 2 subtiles (1 KB each)
#define STAGE(SETK, BUF)                                                          \
    do {                                                                          \
        _Pragma("unroll")                                                         \
        for (int i_ = 0; i_ < 2; ++i_)                                            \
            glds16(gsrc[i_] + (size_t)(SETK) * 1024,                              \
                   lds_raw + (BUF) * 16384 + (w * 2 + i_) * 1024);                \
    } while (0)

// read this wave's 6 fragments of one set from buffer BUF (compile-time)
#define FRAG_READ(FA, FB, BUF)                                                    \
    do {                                                                          \
        const uint8_t* lb_ = lds_raw + (BUF) * 16384 + lane * 16;                 \
        _Pragma("unroll")                                                         \
        for (int i_ = 0; i_ < 4; ++i_)                                            \
            FA[i_] = *(const I4*)(lb_ + (wr4 + i_) * 1024);                       \
        _Pragma("unroll")                                                         \
        for (int j_ = 0; j_ < 2; ++j_)                                            \
            FB[j_] = *(const I4*)(lb_ + 8192 + (wc2 + j_) * 1024);                \
    } while (0)

// MFMA cluster wrapped in setprio (T5): scheduler favors the MFMA-entering
// wave over its SIMD-sibling doing stage/ds_read.
#define MFMA_SET(FA, FB)                                                          \
    do {                                                                          \
        __builtin_amdgcn_s_setprio(1);                                            \
        _Pragma("unroll")                                                         \
        for (int i_ = 0; i_ < 4; ++i_)                                            \
            _Pragma("unroll")                                                     \
            for (int j_ = 0; j_ < 2; ++j_)                                        \
                acc[i_][j_] = __builtin_amdgcn_mfma_i32_32x32x32_i8(              \
                    FA[i_], FB[j_], acc[i_][j_], 0, 0, 0);                        \
        __builtin_amdgcn_s_setprio(0);                                            \
    } while (0)

__global__ __launch_bounds__(512, 2) void gemm_lds(
    const uint8_t* __restrict__ Xp,   // fragment-ordered
    const uint8_t* __restrict__ Wp,   // fragment-ordered
    const int* __restrict__ t, const int* __restrict__ nsh,
    const int* __restrict__ amin, const int* __restrict__ amax,
    int* __restrict__ out) {

    const int bn = blockIdx.x;       // 0..15 (OUT tiles of 256) — fast axis
    const int bm = blockIdx.y;       // 0..31
    const int tid = threadIdx.x;
    const int lane = tid & 63;
    const int w = tid >> 6;          // wave 0..7
    const int wr = w >> 2;           // wave row (0..1): rows wr*128..+128
    const int wc = w & 3;            // wave col (0..3): cols wc*64..+64
    const int wr4 = wr * 4;
    const int wc2 = wc * 2;

    __shared__ uint8_t lds_raw[65536];  // 4 buffers x (8 A + 8 B subtiles) x 1 KB

    // wave w stages subtiles s = 2w, 2w+1 (s<8: A row-tiles; s>=8: B col-tiles)
    const uint8_t* gsrc[2];
#pragma unroll
    for (int i = 0; i < 2; ++i) {
        const int s = w * 2 + i;
        gsrc[i] = (s < 8) ? Xp + ((size_t)(bm * 8 + s) << 17) + lane * 16
                          : Wp + ((size_t)(bn * 8 + (s - 8)) << 17) + lane * 16;
    }

    I16 acc[4][2];
#pragma unroll
    for (int i = 0; i < 4; ++i)
#pragma unroll
        for (int j = 0; j < 2; ++j)
#pragma unroll
            for (int r = 0; r < 16; ++r) acc[i][j][r] = 0;

    I4 a0[4], b0[2], a1[4], b1[2];

    // prologue: stage sets 0..2 (6 vmem/wave), confirm set 0, preload its frags
    STAGE(0, 0);
    STAGE(1, 1);
    STAGE(2, 2);
    VMW4();
    BARRIER();
    FRAG_READ(a0, b0, 0);

    // main loop: 4 sets/iter. Phase P_k: vmcnt(2) confirms set k+1 (set k+2
    // still in flight), barrier, stage k+3, preload frags k+1, MFMA set k.
#pragma unroll 1
    for (int kk = 0; kk < 124; kk += 4) {
        VMW2(); BARRIER();
        STAGE(kk + 3, 3);
        FRAG_READ(a1, b1, 1);
        MFMA_SET(a0, b0);       // set kk
        SCHEDB();
        VMW2(); BARRIER();
        STAGE(kk + 4, 0);
        FRAG_READ(a0, b0, 2);
        MFMA_SET(a1, b1);       // set kk+1
        SCHEDB();
        VMW2(); BARRIER();
        STAGE(kk + 5, 1);
        FRAG_READ(a1, b1, 3);
        MFMA_SET(a0, b0);       // set kk+2
        SCHEDB();
        VMW2(); BARRIER();
        STAGE(kk + 6, 2);
        FRAG_READ(a0, b0, 0);
        MFMA_SET(a1, b1);       // set kk+3
        SCHEDB();
    }
    // peel: sets 124..127 (stages 127; vmcnt tapers 2,2,0)
    VMW2(); BARRIER();
    STAGE(127, 3);
    FRAG_READ(a1, b1, 1);       // set 125
    MFMA_SET(a0, b0);           // set 124
    SCHEDB();
    VMW2(); BARRIER();
    FRAG_READ(a0, b0, 2);       // set 126
    MFMA_SET(a1, b1);           // set 125
    SCHEDB();
    VMW0(); BARRIER();
    FRAG_READ(a1, b1, 3);       // set 127
    MFMA_SET(a0, b0);           // set 126
    SCHEDB();
    MFMA_SET(a1, b1);           // set 127

    // epilogue: 32x32 C/D layout col=lane&31, row=(reg&3)+8*(reg>>2)+4*(lane>>5)
#pragma unroll
    for (int j = 0; j < 2; ++j) {
        const int o = bn * 256 + wc2 * 32 + j * 32 + (lane & 31);
        const int tt = t[o];
        const int sh = -nsh[o];
        const int mn = amin[o];
        const int mx = amax[o];
#pragma unroll
        for (int i = 0; i < 4; ++i) {
            const int rowbase = bm * 256 + wr4 * 32 + i * 32 + 4 * (lane >> 5);
#pragma unroll
            for (int r = 0; r < 16; ++r) {
                const int row = rowbase + (r & 3) + 8 * (r >> 2);
                int v = acc[i][j][r] + tt;
                v >>= sh;
                v = v < mn ? mn : (v > mx ? mx : v);
                __builtin_nontemporal_store(v, &out[(size_t)row * OUTDIM + o]);
            }
        }
    }
}

extern "C" void kernel_launch(void* const* d_in, const int* in_sizes, int n_in,
                              void* d_out, int out_size, void* d_ws, size_t ws_size,
                              hipStream_t stream) {
    const int* x = (const int*)d_in[0];
    const int* W = (const int*)d_in[1];
    const int* t = (const int*)d_in[2];
    const int* n = (const int*)d_in[3];
    const int* amin = (const int*)d_in[4];
    const int* amax = (const int*)d_in[5];
    int* out = (int*)d_out;

    uint8_t* xp = (uint8_t*)d_ws;                    // 33554432 B (fragment order)
    uint8_t* wp = xp + (size_t)BDIM * INDIM;         // 16777216 B (fragment order)

    pack_lds<<<1536, 256, 0, stream>>>(x, W, (uint32_t*)xp, (uint32_t*)wp);

    dim3 grid(OUTDIM / 256, BDIM / 256);  // (16 bn fast, 32 bm) = 512 blocks
    gemm_lds<<<grid, 512, 0, stream>>>(xp, wp, t, n, amin, amax, out);
}